// Round 11
// baseline (663.628 us; speedup 1.0000x reference)
//
#include <hip/hip_runtime.h>
#include <cmath>

// B=8, Cin=16, H=W=128, Cout=64, E=16, K=2
typedef __attribute__((ext_vector_type(8))) short bf16x8;   // MFMA A/B frag
typedef __attribute__((ext_vector_type(4))) float f32x4;    // MFMA C/D frag

static __device__ __forceinline__ unsigned int f2bf(float f) {
    union { float f; unsigned int u; } v; v.f = f;
    unsigned int r = v.u + 0x7FFFu + ((v.u >> 16) & 1u);   // round-to-nearest-even
    return r >> 16;
}

// Pack 16 floats -> 16 bf16 -> two 16B LDS stores
static __device__ __forceinline__ void pack16(unsigned short* d, const float* v) {
    uint4 a, b2;
    a.x  = f2bf(v[0])  | (f2bf(v[1])  << 16);
    a.y  = f2bf(v[2])  | (f2bf(v[3])  << 16);
    a.z  = f2bf(v[4])  | (f2bf(v[5])  << 16);
    a.w  = f2bf(v[6])  | (f2bf(v[7])  << 16);
    b2.x = f2bf(v[8])  | (f2bf(v[9])  << 16);
    b2.y = f2bf(v[10]) | (f2bf(v[11]) << 16);
    b2.z = f2bf(v[12]) | (f2bf(v[13]) << 16);
    b2.w = f2bf(v[14]) | (f2bf(v[15]) << 16);
    *(uint4*)d       = a;
    *(uint4*)(d + 8) = b2;
}

// ---- prep: ew [16][64][144] fp32 + eb -> wb chunks [e][ks][nf][quad][lq] x 8 bf16 ----
// K-PERMUTED layout: k' = ky*48 + kx*16 + ci  (so im2col can write 16-channel runs
// with ds_write_b128). Chunk (e,ks,nf,quad,lq) holds k' = ks*32+quad*8 .. +7 for
// n = nf*16+lq. k'==144 holds bias (pairs with A's 1.0 column), k'>144 zero.
__global__ __launch_bounds__(256) void prep_w_kernel(const float* __restrict__ ew,
                                                     const float* __restrict__ eb,
                                                     unsigned short* __restrict__ wb) {
    const int c = blockIdx.x * 256 + threadIdx.x;
    if (c >= 20480) return;                     // 16 e * 1280 chunks
    const int e    = c / 1280;
    const int r    = c - e * 1280;
    const int ks   = r >> 8;                    // 0..4
    const int nf   = (r >> 6) & 3;
    const int quad = (r >> 4) & 3;
    const int lq   = r & 15;
    const int n    = nf * 16 + lq;
    const int k0   = ks * 32 + quad * 8;        // aligned-8 block of k'
    uint4 dv = make_uint4(0u, 0u, 0u, 0u);
    if (k0 < 144) {
        // k' block never crosses a (ky,kx) boundary (16-sized ci runs, 8-aligned k0)
        const int ky  = k0 / 48;
        const int kx  = (k0 >> 4) % 3;
        const int ci0 = k0 & 15;                // 0 or 8
        // source k = ci*9 + ky*3 + kx  (OIHW [E][64][16][3][3])
        const float* s = ew + (e * 64 + n) * 144 + ci0 * 9 + ky * 3 + kx;
        float v[8];
        #pragma unroll
        for (int j = 0; j < 8; ++j) v[j] = s[j * 9];
        dv.x = f2bf(v[0]) | (f2bf(v[1]) << 16);
        dv.y = f2bf(v[2]) | (f2bf(v[3]) << 16);
        dv.z = f2bf(v[4]) | (f2bf(v[5]) << 16);
        dv.w = f2bf(v[6]) | (f2bf(v[7]) << 16);
    } else if (k0 == 144) {
        dv.x = f2bf(eb[e * 64 + n]);            // bias column
    }
    *(uint4*)(wb + c * 8) = dv;
}

// ---- main: M=64 dense per-expert GEMM, A served from LDS (no register pin) ----
// grid: 2048 = b(8) x row(128) x half(2); block: 256 thr = 4 waves (wave = n-frag)
// Round-10 measured: VGPR=84, zero spill, 203 us, everything <10% busy, occ 29%
// -> LATENCY-bound (12 waves/CU, LDS 44KB = 3 blocks/CU was the cap).
// THIS ROUND: alias outt (18.4KB) into Ab+wexp space (both dead after e-loop;
// extra barrier guards the union) -> LDS 25.6KB -> 6 blocks/CU = 24 waves/CU.
// launch_bounds(256,6) caps regs at 85 (measured need: 84) so VGPRs also allow
// 6 waves/SIMD. E-loop body byte-identical to round 10.
__global__ __launch_bounds__(256, 6) void moe_dense_kernel(
    const float* __restrict__ x,              // [8][16][128][128]
    const float* __restrict__ gw,             // [16][16]
    const float* __restrict__ gb,             // [16]
    const unsigned short* __restrict__ wb,    // [20480 chunks] bf16 (see prep)
    float* __restrict__ out,                  // [8][64][128][128]
    float* __restrict__ logits_out)           // [8][16][128][128]
{
    // 25,600 B union: [ Ab 21,504 B | wexp 4,096 B ] ; outt (18,432 B) aliases front
    __shared__ __align__(16) unsigned char smem0[64 * 168 * 2 + 16 * 64 * 4];
    unsigned short* Ab   = (unsigned short*)smem0;            // [64][168] bf16
    float*          wexp = (float*)(smem0 + 64 * 168 * 2);    // [e][px] gate weight
    float*          outt = (float*)smem0;                     // [64][72] f32 (post-loop)

    const int tid = threadIdx.x;
    // T1 XCD swizzle (bijective: 2048 % 8 == 0): XCD i owns a contiguous bid range
    // -> adjacent rows/halves share halo rows + x panels in the same L2.
    const int bid = (blockIdx.x & 7) * 256 + (blockIdx.x >> 3);
    const int b   = bid >> 8;
    const int row = (bid >> 1) & 127;
    const int px0 = (bid & 1) << 6;

    const int lane = tid & 63;
    const int wave = tid >> 6;           // 0..3 = n-frag
    const int quad = lane >> 4;
    const int lq   = lane & 15;
    const int n    = lq + 16 * wave;     // this lane's cout

    const int px  = lane;
    const int col = px0 + px;

    // ---- phase 1 (single barrier at end): wave-specialized ----
    if (wave < 3) {
        // im2col for ky = wave; A row layout: k' = ky*48 + kx*16 + ci
        const int ky = wave;
        const int gr = row - 1 + ky;
        unsigned short* dst = Ab + px * 168 + ky * 48;
        if (gr < 0 || gr > 127) {        // wave-uniform branch (row 0 / row 127)
            const uint4 z = make_uint4(0u, 0u, 0u, 0u);
            *(uint4*)(dst)      = z; *(uint4*)(dst + 8)  = z;
            *(uint4*)(dst + 16) = z; *(uint4*)(dst + 24) = z;
            *(uint4*)(dst + 32) = z; *(uint4*)(dst + 40) = z;
        } else {
            float L[16], Mv[16], R[16];
            const float* xr = x + ((b * 16) * 128 + gr) * 128 + col;
            #pragma unroll
            for (int ci = 0; ci < 16; ++ci) {
                const float* p = xr + ci * 16384;
                Mv[ci] = p[0];
                L[ci]  = (col > 0)   ? p[-1] : 0.f;
                R[ci]  = (col < 127) ? p[1]  : 0.f;
            }
            pack16(dst,      L);         // kx = 0
            pack16(dst + 16, Mv);        // kx = 1
            pack16(dst + 32, R);         // kx = 2
        }
    } else {
        // gate logits + top-2 routing + logits_out + A k-pad, all in one wave
        // zero wexp first (this wave owns it pre-barrier; no ordering hazard)
        const float4 z4 = make_float4(0.f, 0.f, 0.f, 0.f);
        #pragma unroll
        for (int j = 0; j < 4; ++j)
            *(float4*)&wexp[(j * 64 + lane) * 4] = z4;
        float xv[16];
        const float* xp = x + (b * 16) * 16384 + row * 128 + col;
        #pragma unroll
        for (int ci = 0; ci < 16; ++ci) xv[ci] = xp[ci * 16384];
        float l[16];
        const int rbase = ((b * 16) * 128 + row) * 128 + col;
        #pragma unroll
        for (int o = 0; o < 16; ++o) {
            float acc = gb[o];
            #pragma unroll
            for (int i = 0; i < 16; ++i) acc += gw[o * 16 + i] * xv[i];
            l[o] = acc;
            logits_out[rbase + o * 16384] = acc;
        }
        float m = l[0];
        #pragma unroll
        for (int o = 1; o < 16; ++o) m = fmaxf(m, l[o]);
        float p0 = expf(l[0] - m), p1 = -1.f;
        int i0 = 0, i1 = 0;
        #pragma unroll
        for (int o = 1; o < 16; ++o) {
            float pv = expf(l[o] - m);
            if (pv > p0)      { p1 = p0; i1 = i0; p0 = pv; i0 = o; }
            else if (pv > p1) { p1 = pv; i1 = o; }
        }
        const float ws = p0 + p1;
        wexp[i0 * 64 + px] = p0 / ws;
        wexp[i1 * 64 + px] = p1 / ws;
        // A k-pad: k'144 = 1.0 (bias column), 145..167 = 0
        const uint4 z   = make_uint4(0u, 0u, 0u, 0u);
        const uint4 one = make_uint4(0x00003F80u, 0u, 0u, 0u);
        *(uint4*)(Ab + px * 168 + 144) = one;
        *(uint4*)(Ab + px * 168 + 152) = z;
        *(uint4*)(Ab + px * 168 + 160) = z;
    }

    // B prefetch, pre-barrier (depends only on wb): 2-deep double buffer
    const unsigned short* bp = wb + wave * 512 + lane * 8;   // chunk (e,ks,nf=wave,quad,lq)
    bf16x8 b0[5], b1[5];
    #pragma unroll
    for (int ks = 0; ks < 5; ++ks) b0[ks] = *(const bf16x8*)(bp + ks * 2048);
    #pragma unroll
    for (int ks = 0; ks < 5; ++ks) b1[ks] = *(const bf16x8*)(bp + 10240 + ks * 2048);

    __syncthreads();                     // Ab + wexp ready (persist through e-loop)

    // ---- phase 3: dense e-loop; A from LDS per (e,mt); no pins anywhere ----
    const unsigned short* arow = Ab + lq * 168 + quad * 8;   // + mt*16*168 per tile
    f32x4 facc[4];
    #pragma unroll
    for (int mt = 0; mt < 4; ++mt) facc[mt] = (f32x4){0.f, 0.f, 0.f, 0.f};

    #pragma unroll 1
    for (int e = 0; e < 16; e += 2) {
        // expert e (uses b0)
        __builtin_amdgcn_s_setprio(1);
        #pragma unroll
        for (int mt = 0; mt < 4; ++mt) {
            const unsigned short* ar = arow + mt * (16 * 168);
            bf16x8 a0 = *(const bf16x8*)(ar);
            bf16x8 a1 = *(const bf16x8*)(ar + 32);
            bf16x8 a2 = *(const bf16x8*)(ar + 64);
            bf16x8 a3 = *(const bf16x8*)(ar + 96);
            bf16x8 a4 = *(const bf16x8*)(ar + 128);
            const f32x4 wv = *(const f32x4*)&wexp[e * 64 + mt * 16 + quad * 4];
            f32x4 acc = {0.f, 0.f, 0.f, 0.f};
            acc = __builtin_amdgcn_mfma_f32_16x16x32_bf16(a0, b0[0], acc, 0, 0, 0);
            acc = __builtin_amdgcn_mfma_f32_16x16x32_bf16(a1, b0[1], acc, 0, 0, 0);
            acc = __builtin_amdgcn_mfma_f32_16x16x32_bf16(a2, b0[2], acc, 0, 0, 0);
            acc = __builtin_amdgcn_mfma_f32_16x16x32_bf16(a3, b0[3], acc, 0, 0, 0);
            acc = __builtin_amdgcn_mfma_f32_16x16x32_bf16(a4, b0[4], acc, 0, 0, 0);
            #pragma unroll
            for (int r = 0; r < 4; ++r)             // C/D: row(px)=quad*4+r, col(c)=lq
                facc[mt][r] += wv[r] * acc[r];
        }
        __builtin_amdgcn_s_setprio(0);
        if (e < 14) {                    // prefetch expert e+2 into b0
            const unsigned short* p = bp + (e + 2) * 10240;
            #pragma unroll
            for (int ks = 0; ks < 5; ++ks) b0[ks] = *(const bf16x8*)(p + ks * 2048);
        }
        // expert e+1 (uses b1)
        __builtin_amdgcn_s_setprio(1);
        #pragma unroll
        for (int mt = 0; mt < 4; ++mt) {
            const unsigned short* ar = arow + mt * (16 * 168);
            bf16x8 a0 = *(const bf16x8*)(ar);
            bf16x8 a1 = *(const bf16x8*)(ar + 32);
            bf16x8 a2 = *(const bf16x8*)(ar + 64);
            bf16x8 a3 = *(const bf16x8*)(ar + 96);
            bf16x8 a4 = *(const bf16x8*)(ar + 128);
            const f32x4 wv = *(const f32x4*)&wexp[(e + 1) * 64 + mt * 16 + quad * 4];
            f32x4 acc = {0.f, 0.f, 0.f, 0.f};
            acc = __builtin_amdgcn_mfma_f32_16x16x32_bf16(a0, b1[0], acc, 0, 0, 0);
            acc = __builtin_amdgcn_mfma_f32_16x16x32_bf16(a1, b1[1], acc, 0, 0, 0);
            acc = __builtin_amdgcn_mfma_f32_16x16x32_bf16(a2, b1[2], acc, 0, 0, 0);
            acc = __builtin_amdgcn_mfma_f32_16x16x32_bf16(a3, b1[3], acc, 0, 0, 0);
            acc = __builtin_amdgcn_mfma_f32_16x16x32_bf16(a4, b1[4], acc, 0, 0, 0);
            #pragma unroll
            for (int r = 0; r < 4; ++r)
                facc[mt][r] += wv[r] * acc[r];
        }
        __builtin_amdgcn_s_setprio(0);
        if (e < 13) {                    // prefetch expert e+3 into b1
            const unsigned short* p = bp + (e + 3) * 10240;
            #pragma unroll
            for (int ks = 0; ks < 5; ++ks) b1[ks] = *(const bf16x8*)(p + ks * 2048);
        }
    }

    __syncthreads();                     // ALL waves done reading Ab/wexp -> outt may alias

    // ---- phase 4: transpose bounce in [c][px+pad] layout, all-b128 ----
    // facc[mt] holds px = mt*16+quad*4+{0..3} for cout n -> one ds_write_b128 each.
    // Stride 72 dwords: slot-group (2n+4mt+quad)%8 -> exactly 8 lanes/group =
    // wave64 b128 conflict-free minimum. Read side (2c+p4)%8 likewise.
    #pragma unroll
    for (int mt = 0; mt < 4; ++mt)
        *(f32x4*)&outt[n * 72 + mt * 16 + quad * 4] = facc[mt];
    __syncthreads();
    #pragma unroll
    for (int j = 0; j < 4; ++j) {
        const int idx = j * 256 + tid;          // 0..1023
        const int c   = idx >> 4;               // cout 0..63
        const int p4  = idx & 15;               // px/4 group 0..15
        const f32x4 v = *(const f32x4*)&outt[c * 72 + p4 * 4];    // ds_read_b128
        *(f32x4*)&out[((b * 64 + c) * 128 + row) * 128 + px0 + p4 * 4] = v;
    }
}

extern "C" void kernel_launch(void* const* d_in, const int* in_sizes, int n_in,
                              void* d_out, int out_size, void* d_ws, size_t ws_size,
                              hipStream_t stream) {
    const float* x  = (const float*)d_in[0];
    const float* gw = (const float*)d_in[1];
    const float* gb = (const float*)d_in[2];
    const float* ew = (const float*)d_in[3];
    const float* eb = (const float*)d_in[4];
    float* out        = (float*)d_out;
    float* logits_out = out + 8 * 64 * 128 * 128;
    unsigned short* wb = (unsigned short*)d_ws;      // 20480 chunks * 16 B = 327,680 B

    prep_w_kernel<<<dim3(80), dim3(256), 0, stream>>>(ew, eb, wb);
    moe_dense_kernel<<<dim3(2048), dim3(256), 0, stream>>>(
        x, gw, gb, wb, out, logits_out);
}

// Round 12
// 453.294 us; speedup vs baseline: 1.4640x; 1.4640x over previous
//
#include <hip/hip_runtime.h>
#include <cmath>

// B=8, Cin=16, H=W=128, Cout=64, E=16, K=2
typedef __attribute__((ext_vector_type(8))) short bf16x8;   // MFMA A/B frag
typedef __attribute__((ext_vector_type(4))) float f32x4;    // MFMA C/D frag

static __device__ __forceinline__ unsigned int f2bf(float f) {
    union { float f; unsigned int u; } v; v.f = f;
    unsigned int r = v.u + 0x7FFFu + ((v.u >> 16) & 1u);   // round-to-nearest-even
    return r >> 16;
}

// Pack 16 floats -> 16 bf16 -> two 16B LDS stores
static __device__ __forceinline__ void pack16(unsigned short* d, const float* v) {
    uint4 a, b2;
    a.x  = f2bf(v[0])  | (f2bf(v[1])  << 16);
    a.y  = f2bf(v[2])  | (f2bf(v[3])  << 16);
    a.z  = f2bf(v[4])  | (f2bf(v[5])  << 16);
    a.w  = f2bf(v[6])  | (f2bf(v[7])  << 16);
    b2.x = f2bf(v[8])  | (f2bf(v[9])  << 16);
    b2.y = f2bf(v[10]) | (f2bf(v[11]) << 16);
    b2.z = f2bf(v[12]) | (f2bf(v[13]) << 16);
    b2.w = f2bf(v[14]) | (f2bf(v[15]) << 16);
    *(uint4*)d       = a;
    *(uint4*)(d + 8) = b2;
}

// ---- prep: ew [16][64][144] fp32 + eb -> wb chunks [e][ks][nf][quad][lq] x 8 bf16 ----
// K-PERMUTED layout: k' = ky*48 + kx*16 + ci  (so im2col can write 16-channel runs
// with ds_write_b128). Chunk (e,ks,nf,quad,lq) holds k' = ks*32+quad*8 .. +7 for
// n = nf*16+lq. k'==144 holds bias (pairs with A's 1.0 column), k'>144 zero.
__global__ __launch_bounds__(256) void prep_w_kernel(const float* __restrict__ ew,
                                                     const float* __restrict__ eb,
                                                     unsigned short* __restrict__ wb) {
    const int c = blockIdx.x * 256 + threadIdx.x;
    if (c >= 20480) return;                     // 16 e * 1280 chunks
    const int e    = c / 1280;
    const int r    = c - e * 1280;
    const int ks   = r >> 8;                    // 0..4
    const int nf   = (r >> 6) & 3;
    const int quad = (r >> 4) & 3;
    const int lq   = r & 15;
    const int n    = nf * 16 + lq;
    const int k0   = ks * 32 + quad * 8;        // aligned-8 block of k'
    uint4 dv = make_uint4(0u, 0u, 0u, 0u);
    if (k0 < 144) {
        // k' block never crosses a (ky,kx) boundary (16-sized ci runs, 8-aligned k0)
        const int ky  = k0 / 48;
        const int kx  = (k0 >> 4) % 3;
        const int ci0 = k0 & 15;                // 0 or 8
        // source k = ci*9 + ky*3 + kx  (OIHW [E][64][16][3][3])
        const float* s = ew + (e * 64 + n) * 144 + ci0 * 9 + ky * 3 + kx;
        float v[8];
        #pragma unroll
        for (int j = 0; j < 8; ++j) v[j] = s[j * 9];
        dv.x = f2bf(v[0]) | (f2bf(v[1]) << 16);
        dv.y = f2bf(v[2]) | (f2bf(v[3]) << 16);
        dv.z = f2bf(v[4]) | (f2bf(v[5]) << 16);
        dv.w = f2bf(v[6]) | (f2bf(v[7]) << 16);
    } else if (k0 == 144) {
        dv.x = f2bf(eb[e * 64 + n]);            // bias column
    }
    *(uint4*)(wb + c * 8) = dv;
}

// One mt step: issue NEXT mt's A loads, then MFMA on CURRENT buffer.
// The loads-first order lets the compiler wait with lgkmcnt(5) (not 0) before
// the MFMAs -- next-step LDS latency hides under this step's matrix work.
#define ASTEP(CUR, NXT, MTC, MTN, BB, WE) do {                                  \
    const unsigned short* arn_ = arow + (MTN) * 2688;                           \
    NXT[0] = *(const bf16x8*)(arn_);                                            \
    NXT[1] = *(const bf16x8*)(arn_ + 32);                                       \
    NXT[2] = *(const bf16x8*)(arn_ + 64);                                       \
    NXT[3] = *(const bf16x8*)(arn_ + 96);                                       \
    NXT[4] = *(const bf16x8*)(arn_ + 128);                                      \
    const f32x4 wv_ = *(const f32x4*)&wexp[(WE) * 64 + (MTC) * 16 + quad * 4];  \
    f32x4 acc_ = {0.f, 0.f, 0.f, 0.f};                                          \
    acc_ = __builtin_amdgcn_mfma_f32_16x16x32_bf16(CUR[0], BB[0], acc_, 0,0,0); \
    acc_ = __builtin_amdgcn_mfma_f32_16x16x32_bf16(CUR[1], BB[1], acc_, 0,0,0); \
    acc_ = __builtin_amdgcn_mfma_f32_16x16x32_bf16(CUR[2], BB[2], acc_, 0,0,0); \
    acc_ = __builtin_amdgcn_mfma_f32_16x16x32_bf16(CUR[3], BB[3], acc_, 0,0,0); \
    acc_ = __builtin_amdgcn_mfma_f32_16x16x32_bf16(CUR[4], BB[4], acc_, 0,0,0); \
    facc[MTC][0] += wv_[0] * acc_[0];                                           \
    facc[MTC][1] += wv_[1] * acc_[1];                                           \
    facc[MTC][2] += wv_[2] * acc_[2];                                           \
    facc[MTC][3] += wv_[3] * acc_[3];                                           \
} while (0)

// ---- main: M=64 dense per-expert GEMM, A from LDS with mt-pipelined reads ----
// grid: 2048 = b(8) x row(128) x half(2); block: 256 thr = 4 waves (wave = n-frag)
// Round-10: VGPR 84, zero spill, 203 us, all pipes <10% -> latency-bound @12 w/CU.
// Round-11: launch_bounds(256,6) squeezed regs to 40 -> spill storm (996MB, 605us).
// THIS ROUND: (a) keep LDS alias (outt over Ab/wexp post-loop) -> 25.6KB -> LDS
// allows 6 blocks/CU; (b) launch_bounds(256,4): cap 128 >= live ~119, HW gives
// 4 waves/SIMD = 16 waves/CU (+33%); (c) explicit A double-buffer across mt
// (aa/an) pipelines ds_read ahead of MFMAs -> lgkmcnt(5) waits instead of drains.
__global__ __launch_bounds__(256, 4) void moe_dense_kernel(
    const float* __restrict__ x,              // [8][16][128][128]
    const float* __restrict__ gw,             // [16][16]
    const float* __restrict__ gb,             // [16]
    const unsigned short* __restrict__ wb,    // [20480 chunks] bf16 (see prep)
    float* __restrict__ out,                  // [8][64][128][128]
    float* __restrict__ logits_out)           // [8][16][128][128]
{
    // 25,600 B union: [ Ab 21,504 B | wexp 4,096 B ] ; outt (18,432 B) aliases front
    __shared__ __align__(16) unsigned char smem0[64 * 168 * 2 + 16 * 64 * 4];
    unsigned short* Ab   = (unsigned short*)smem0;            // [64][168] bf16
    float*          wexp = (float*)(smem0 + 64 * 168 * 2);    // [e][px] gate weight
    float*          outt = (float*)smem0;                     // [64][72] f32 (post-loop)

    const int tid = threadIdx.x;
    // T1 XCD swizzle (bijective: 2048 % 8 == 0): XCD i owns a contiguous bid range
    // -> adjacent rows/halves share halo rows + x panels in the same L2.
    const int bid = (blockIdx.x & 7) * 256 + (blockIdx.x >> 3);
    const int b   = bid >> 8;
    const int row = (bid >> 1) & 127;
    const int px0 = (bid & 1) << 6;

    const int lane = tid & 63;
    const int wave = tid >> 6;           // 0..3 = n-frag
    const int quad = lane >> 4;
    const int lq   = lane & 15;
    const int n    = lq + 16 * wave;     // this lane's cout

    const int px  = lane;
    const int col = px0 + px;

    // ---- phase 1 (single barrier at end): wave-specialized ----
    if (wave < 3) {
        // im2col for ky = wave; A row layout: k' = ky*48 + kx*16 + ci
        const int ky = wave;
        const int gr = row - 1 + ky;
        unsigned short* dst = Ab + px * 168 + ky * 48;
        if (gr < 0 || gr > 127) {        // wave-uniform branch (row 0 / row 127)
            const uint4 z = make_uint4(0u, 0u, 0u, 0u);
            *(uint4*)(dst)      = z; *(uint4*)(dst + 8)  = z;
            *(uint4*)(dst + 16) = z; *(uint4*)(dst + 24) = z;
            *(uint4*)(dst + 32) = z; *(uint4*)(dst + 40) = z;
        } else {
            float L[16], Mv[16], R[16];
            const float* xr = x + ((b * 16) * 128 + gr) * 128 + col;
            #pragma unroll
            for (int ci = 0; ci < 16; ++ci) {
                const float* p = xr + ci * 16384;
                Mv[ci] = p[0];
                L[ci]  = (col > 0)   ? p[-1] : 0.f;
                R[ci]  = (col < 127) ? p[1]  : 0.f;
            }
            pack16(dst,      L);         // kx = 0
            pack16(dst + 16, Mv);        // kx = 1
            pack16(dst + 32, R);         // kx = 2
        }
    } else {
        // gate logits + top-2 routing + logits_out + A k-pad, all in one wave
        // zero wexp first (this wave owns it pre-barrier; no ordering hazard)
        const float4 z4 = make_float4(0.f, 0.f, 0.f, 0.f);
        #pragma unroll
        for (int j = 0; j < 4; ++j)
            *(float4*)&wexp[(j * 64 + lane) * 4] = z4;
        float xv[16];
        const float* xp = x + (b * 16) * 16384 + row * 128 + col;
        #pragma unroll
        for (int ci = 0; ci < 16; ++ci) xv[ci] = xp[ci * 16384];
        float l[16];
        const int rbase = ((b * 16) * 128 + row) * 128 + col;
        #pragma unroll
        for (int o = 0; o < 16; ++o) {
            float acc = gb[o];
            #pragma unroll
            for (int i = 0; i < 16; ++i) acc += gw[o * 16 + i] * xv[i];
            l[o] = acc;
            logits_out[rbase + o * 16384] = acc;
        }
        float m = l[0];
        #pragma unroll
        for (int o = 1; o < 16; ++o) m = fmaxf(m, l[o]);
        float p0 = expf(l[0] - m), p1 = -1.f;
        int i0 = 0, i1 = 0;
        #pragma unroll
        for (int o = 1; o < 16; ++o) {
            float pv = expf(l[o] - m);
            if (pv > p0)      { p1 = p0; i1 = i0; p0 = pv; i0 = o; }
            else if (pv > p1) { p1 = pv; i1 = o; }
        }
        const float ws = p0 + p1;
        wexp[i0 * 64 + px] = p0 / ws;
        wexp[i1 * 64 + px] = p1 / ws;
        // A k-pad: k'144 = 1.0 (bias column), 145..167 = 0
        const uint4 z   = make_uint4(0u, 0u, 0u, 0u);
        const uint4 one = make_uint4(0x00003F80u, 0u, 0u, 0u);
        *(uint4*)(Ab + px * 168 + 144) = one;
        *(uint4*)(Ab + px * 168 + 152) = z;
        *(uint4*)(Ab + px * 168 + 160) = z;
    }

    // B prefetch, pre-barrier (depends only on wb): 2-deep double buffer
    const unsigned short* bp = wb + wave * 512 + lane * 8;   // chunk (e,ks,nf=wave,quad,lq)
    bf16x8 b0[5], b1[5];
    #pragma unroll
    for (int ks = 0; ks < 5; ++ks) b0[ks] = *(const bf16x8*)(bp + ks * 2048);
    #pragma unroll
    for (int ks = 0; ks < 5; ++ks) b1[ks] = *(const bf16x8*)(bp + 10240 + ks * 2048);

    __syncthreads();                     // Ab + wexp ready (persist through e-loop)

    // ---- phase 3: dense e-loop; A pipelined from LDS (aa/an rotation) ----
    const unsigned short* arow = Ab + lq * 168 + quad * 8;   // + mt*2688 per tile
    f32x4 facc[4];
    #pragma unroll
    for (int mt = 0; mt < 4; ++mt) facc[mt] = (f32x4){0.f, 0.f, 0.f, 0.f};

    bf16x8 aa[5], an[5];
    #pragma unroll
    for (int ks = 0; ks < 5; ++ks) aa[ks] = *(const bf16x8*)(arow + ks * 32);  // mt0

    #pragma unroll 1
    for (int e = 0; e < 16; e += 2) {
        // expert e (uses b0); mt sequence 0,1,2,3 with aa/an rotation
        __builtin_amdgcn_s_setprio(1);
        ASTEP(aa, an, 0, 1, b0, e);
        ASTEP(an, aa, 1, 2, b0, e);
        ASTEP(aa, an, 2, 3, b0, e);
        ASTEP(an, aa, 3, 0, b0, e);      // preloads mt0 for expert e+1
        __builtin_amdgcn_s_setprio(0);
        if (e < 14) {                    // prefetch expert e+2 into b0
            const unsigned short* p = bp + (e + 2) * 10240;
            #pragma unroll
            for (int ks = 0; ks < 5; ++ks) b0[ks] = *(const bf16x8*)(p + ks * 2048);
        }
        // expert e+1 (uses b1)
        __builtin_amdgcn_s_setprio(1);
        ASTEP(aa, an, 0, 1, b1, e + 1);
        ASTEP(an, aa, 1, 2, b1, e + 1);
        ASTEP(aa, an, 2, 3, b1, e + 1);
        ASTEP(an, aa, 3, 0, b1, e + 1);  // preloads mt0 for expert e+2
        __builtin_amdgcn_s_setprio(0);
        if (e < 13) {                    // prefetch expert e+3 into b1
            const unsigned short* p = bp + (e + 3) * 10240;
            #pragma unroll
            for (int ks = 0; ks < 5; ++ks) b1[ks] = *(const bf16x8*)(p + ks * 2048);
        }
    }

    __syncthreads();                     // ALL waves done reading Ab/wexp -> outt may alias

    // ---- phase 4: transpose bounce in [c][px+pad] layout, all-b128 ----
    // facc[mt] holds px = mt*16+quad*4+{0..3} for cout n -> one ds_write_b128 each.
    // Stride 72 dwords: slot-group (2n+4mt+quad)%8 -> exactly 8 lanes/group =
    // wave64 b128 conflict-free minimum. Read side (2c+p4)%8 likewise.
    #pragma unroll
    for (int mt = 0; mt < 4; ++mt)
        *(f32x4*)&outt[n * 72 + mt * 16 + quad * 4] = facc[mt];
    __syncthreads();
    #pragma unroll
    for (int j = 0; j < 4; ++j) {
        const int idx = j * 256 + tid;          // 0..1023
        const int c   = idx >> 4;               // cout 0..63
        const int p4  = idx & 15;               // px/4 group 0..15
        const f32x4 v = *(const f32x4*)&outt[c * 72 + p4 * 4];    // ds_read_b128
        *(f32x4*)&out[((b * 64 + c) * 128 + row) * 128 + px0 + p4 * 4] = v;
    }
}

extern "C" void kernel_launch(void* const* d_in, const int* in_sizes, int n_in,
                              void* d_out, int out_size, void* d_ws, size_t ws_size,
                              hipStream_t stream) {
    const float* x  = (const float*)d_in[0];
    const float* gw = (const float*)d_in[1];
    const float* gb = (const float*)d_in[2];
    const float* ew = (const float*)d_in[3];
    const float* eb = (const float*)d_in[4];
    float* out        = (float*)d_out;
    float* logits_out = out + 8 * 64 * 128 * 128;
    unsigned short* wb = (unsigned short*)d_ws;      // 20480 chunks * 16 B = 327,680 B

    prep_w_kernel<<<dim3(80), dim3(256), 0, stream>>>(ew, eb, wb);
    moe_dense_kernel<<<dim3(2048), dim3(256), 0, stream>>>(
        x, gw, gb, wb, out, logits_out);
}

// Round 13
// 332.591 us; speedup vs baseline: 1.9953x; 1.3629x over previous
//
#include <hip/hip_runtime.h>
#include <cmath>

// B=8, Cin=16, H=W=128, Cout=64, E=16, K=2
typedef __attribute__((ext_vector_type(8))) short bf16x8;   // MFMA A/B frag
typedef __attribute__((ext_vector_type(4))) float f32x4;    // MFMA C/D frag

static __device__ __forceinline__ unsigned int f2bf(float f) {
    union { float f; unsigned int u; } v; v.f = f;
    unsigned int r = v.u + 0x7FFFu + ((v.u >> 16) & 1u);   // round-to-nearest-even
    return r >> 16;
}

// Pack 16 floats -> 16 bf16 -> two 16B LDS stores
static __device__ __forceinline__ void pack16(unsigned short* d, const float* v) {
    uint4 a, b2;
    a.x  = f2bf(v[0])  | (f2bf(v[1])  << 16);
    a.y  = f2bf(v[2])  | (f2bf(v[3])  << 16);
    a.z  = f2bf(v[4])  | (f2bf(v[5])  << 16);
    a.w  = f2bf(v[6])  | (f2bf(v[7])  << 16);
    b2.x = f2bf(v[8])  | (f2bf(v[9])  << 16);
    b2.y = f2bf(v[10]) | (f2bf(v[11]) << 16);
    b2.z = f2bf(v[12]) | (f2bf(v[13]) << 16);
    b2.w = f2bf(v[14]) | (f2bf(v[15]) << 16);
    *(uint4*)d       = a;
    *(uint4*)(d + 8) = b2;
}

// ---- prep: ew [16][64][144] fp32 + eb -> wb chunks [e][ks][nf][quad][lq] x 8 bf16 ----
// K-PERMUTED layout: k' = ky*48 + kx*16 + ci  (so im2col can write 16-channel runs
// with ds_write_b128). Chunk (e,ks,nf,quad,lq) holds k' = ks*32+quad*8 .. +7 for
// n = nf*16+lq. k'==144 holds bias (pairs with A's 1.0 column), k'>144 zero.
__global__ __launch_bounds__(256) void prep_w_kernel(const float* __restrict__ ew,
                                                     const float* __restrict__ eb,
                                                     unsigned short* __restrict__ wb) {
    const int c = blockIdx.x * 256 + threadIdx.x;
    if (c >= 20480) return;                     // 16 e * 1280 chunks
    const int e    = c / 1280;
    const int r    = c - e * 1280;
    const int ks   = r >> 8;                    // 0..4
    const int nf   = (r >> 6) & 3;
    const int quad = (r >> 4) & 3;
    const int lq   = r & 15;
    const int n    = nf * 16 + lq;
    const int k0   = ks * 32 + quad * 8;        // aligned-8 block of k'
    uint4 dv = make_uint4(0u, 0u, 0u, 0u);
    if (k0 < 144) {
        // k' block never crosses a (ky,kx) boundary (16-sized ci runs, 8-aligned k0)
        const int ky  = k0 / 48;
        const int kx  = (k0 >> 4) % 3;
        const int ci0 = k0 & 15;                // 0 or 8
        // source k = ci*9 + ky*3 + kx  (OIHW [E][64][16][3][3])
        const float* s = ew + (e * 64 + n) * 144 + ci0 * 9 + ky * 3 + kx;
        float v[8];
        #pragma unroll
        for (int j = 0; j < 8; ++j) v[j] = s[j * 9];
        dv.x = f2bf(v[0]) | (f2bf(v[1]) << 16);
        dv.y = f2bf(v[2]) | (f2bf(v[3]) << 16);
        dv.z = f2bf(v[4]) | (f2bf(v[5]) << 16);
        dv.w = f2bf(v[6]) | (f2bf(v[7]) << 16);
    } else if (k0 == 144) {
        dv.x = f2bf(eb[e * 64 + n]);            // bias column
    }
    *(uint4*)(wb + c * 8) = dv;
}

// ---- main: M=64 dense per-expert GEMM, BASELINE register schedule restored ----
// grid: 2048 = b(8) x row(128) x half(2); block: 256 thr = 4 waves (wave = n-frag)
// REGISTER MODEL (rounds 5/8/9/11/12): arch-VGPR cap = 256 / min_waves_per_SIMD
// (toolchain reserves half the 512 unified file for AGPR when MFMA present):
// (256,2)->128, (256,3)->84, (256,4)->64, (256,6)->40. Live set above cap =
// loop-resident scratch spill (~1 GB/dispatch, 3-5x slowdown).
// THIS KERNEL: the PROVEN 121-us envelope -- af[4][5] "+v" pinned (80) + bn 20 +
// bc 20 + facc 16 ~= 136 live at the 128 cap, B loads strictly AFTER the af-pin
// barrier (the rounds-6/8 pre-barrier prefetch is what pushed peak live to 150
// and spilled af). Only non-register fixes are added vs baseline: k' b128 im2col,
// wave-specialized 1-barrier phase 1, b128 conflict-free epilogue, XCD swizzle.
__global__ __launch_bounds__(256, 2) void moe_dense_kernel(
    const float* __restrict__ x,              // [8][16][128][128]
    const float* __restrict__ gw,             // [16][16]
    const float* __restrict__ gb,             // [16]
    const unsigned short* __restrict__ wb,    // [20480 chunks] bf16 (see prep)
    float* __restrict__ out,                  // [8][64][128][128]
    float* __restrict__ logits_out)           // [8][16][128][128]
{
    // 25,600 B union: [ Ab 21,504 B | wexp 4,096 B ]; outt (18,432 B) aliases Ab.
    // Safe without an extra barrier: ALL Ab reads (af pin) complete before the
    // second barrier; e-loop touches only wexp (not aliased); outt writes are
    // post-e-loop. wexp lives at offset 21,504 -- outside outt's 18,432 B.
    __shared__ __align__(16) unsigned char smem0[64 * 168 * 2 + 16 * 64 * 4];
    unsigned short* Ab   = (unsigned short*)smem0;            // [64][168] bf16
    float*          wexp = (float*)(smem0 + 64 * 168 * 2);    // [e][px] gate weight
    float*          outt = (float*)smem0;                     // [64][72] f32 (post-loop)

    const int tid = threadIdx.x;
    // T1 XCD swizzle (bijective: 2048 % 8 == 0): XCD i owns a contiguous bid range
    // -> adjacent rows/halves share halo rows + x panels in the same L2.
    const int bid = (blockIdx.x & 7) * 256 + (blockIdx.x >> 3);
    const int b   = bid >> 8;
    const int row = (bid >> 1) & 127;
    const int px0 = (bid & 1) << 6;

    const int lane = tid & 63;
    const int wave = tid >> 6;           // 0..3 = n-frag
    const int quad = lane >> 4;
    const int lq   = lane & 15;
    const int n    = lq + 16 * wave;     // this lane's cout

    const int px  = lane;
    const int col = px0 + px;

    // ---- phase 1 (single barrier at end): wave-specialized ----
    if (wave < 3) {
        // im2col for ky = wave; A row layout: k' = ky*48 + kx*16 + ci
        const int ky = wave;
        const int gr = row - 1 + ky;
        unsigned short* dst = Ab + px * 168 + ky * 48;
        if (gr < 0 || gr > 127) {        // wave-uniform branch (row 0 / row 127)
            const uint4 z = make_uint4(0u, 0u, 0u, 0u);
            *(uint4*)(dst)      = z; *(uint4*)(dst + 8)  = z;
            *(uint4*)(dst + 16) = z; *(uint4*)(dst + 24) = z;
            *(uint4*)(dst + 32) = z; *(uint4*)(dst + 40) = z;
        } else {
            float L[16], Mv[16], R[16];
            const float* xr = x + ((b * 16) * 128 + gr) * 128 + col;
            #pragma unroll
            for (int ci = 0; ci < 16; ++ci) {
                const float* p = xr + ci * 16384;
                Mv[ci] = p[0];
                L[ci]  = (col > 0)   ? p[-1] : 0.f;
                R[ci]  = (col < 127) ? p[1]  : 0.f;
            }
            pack16(dst,      L);         // kx = 0
            pack16(dst + 16, Mv);        // kx = 1
            pack16(dst + 32, R);         // kx = 2
        }
    } else {
        // gate logits + top-2 routing + logits_out + A k-pad, all in one wave
        // zero wexp first (this wave owns it pre-barrier; no ordering hazard)
        const float4 z4 = make_float4(0.f, 0.f, 0.f, 0.f);
        #pragma unroll
        for (int j = 0; j < 4; ++j)
            *(float4*)&wexp[(j * 64 + lane) * 4] = z4;
        float xv[16];
        const float* xp = x + (b * 16) * 16384 + row * 128 + col;
        #pragma unroll
        for (int ci = 0; ci < 16; ++ci) xv[ci] = xp[ci * 16384];
        float l[16];
        const int rbase = ((b * 16) * 128 + row) * 128 + col;
        #pragma unroll
        for (int o = 0; o < 16; ++o) {
            float acc = gb[o];
            #pragma unroll
            for (int i = 0; i < 16; ++i) acc += gw[o * 16 + i] * xv[i];
            l[o] = acc;
            logits_out[rbase + o * 16384] = acc;
        }
        float m = l[0];
        #pragma unroll
        for (int o = 1; o < 16; ++o) m = fmaxf(m, l[o]);
        float p0 = expf(l[0] - m), p1 = -1.f;
        int i0 = 0, i1 = 0;
        #pragma unroll
        for (int o = 1; o < 16; ++o) {
            float pv = expf(l[o] - m);
            if (pv > p0)      { p1 = p0; i1 = i0; p0 = pv; i0 = o; }
            else if (pv > p1) { p1 = pv; i1 = o; }
        }
        const float ws = p0 + p1;
        wexp[i0 * 64 + px] = p0 / ws;
        wexp[i1 * 64 + px] = p1 / ws;
        // A k-pad: k'144 = 1.0 (bias column), 145..167 = 0
        const uint4 z   = make_uint4(0u, 0u, 0u, 0u);
        const uint4 one = make_uint4(0x00003F80u, 0u, 0u, 0u);
        *(uint4*)(Ab + px * 168 + 144) = one;
        *(uint4*)(Ab + px * 168 + 152) = z;
        *(uint4*)(Ab + px * 168 + 160) = z;
    }
    __syncthreads();                     // Ab + wexp ready

    // ---- phase 2: A fragments, load once and PIN in VGPRs (baseline pattern) ----
    bf16x8 af[4][5];
    #pragma unroll
    for (int mt = 0; mt < 4; ++mt) {
        const unsigned short* arow = Ab + (mt * 16 + lq) * 168 + quad * 8;
        #pragma unroll
        for (int ks = 0; ks < 5; ++ks) af[mt][ks] = *(const bf16x8*)(arow + ks * 32);
    }
    #pragma unroll
    for (int mt = 0; mt < 4; ++mt)
        #pragma unroll
        for (int ks = 0; ks < 5; ++ks)
            asm volatile("" : "+v"(af[mt][ks]));
    __syncthreads();                     // all Ab reads done -> outt may alias

    // ---- phase 3: dense e-loop, BASELINE schedule: B loads after the pin ----
    const unsigned short* bp = wb + wave * 512 + lane * 8;   // chunk (e,ks,nf=wave,quad,lq)
    bf16x8 bn[5];
    #pragma unroll
    for (int ks = 0; ks < 5; ++ks) bn[ks] = *(const bf16x8*)(bp + ks * 2048);

    f32x4 facc[4];
    #pragma unroll
    for (int mt = 0; mt < 4; ++mt) facc[mt] = (f32x4){0.f, 0.f, 0.f, 0.f};

    for (int e = 0; e < 16; ++e) {
        bf16x8 bc[5];
        #pragma unroll
        for (int ks = 0; ks < 5; ++ks) bc[ks] = bn[ks];
        if (e < 15) {                    // prefetch next expert (contiguous, L2-hot)
            const unsigned short* p = bp + (e + 1) * 10240;
            #pragma unroll
            for (int ks = 0; ks < 5; ++ks) bn[ks] = *(const bf16x8*)(p + ks * 2048);
        }
        __builtin_amdgcn_s_setprio(1);
        #pragma unroll
        for (int mt = 0; mt < 4; ++mt) {
            const f32x4 wv = *(const f32x4*)&wexp[e * 64 + mt * 16 + quad * 4];
            f32x4 acc = {0.f, 0.f, 0.f, 0.f};
            #pragma unroll
            for (int ks = 0; ks < 5; ++ks)
                acc = __builtin_amdgcn_mfma_f32_16x16x32_bf16(af[mt][ks], bc[ks], acc, 0, 0, 0);
            #pragma unroll
            for (int r = 0; r < 4; ++r)             // C/D: row(px)=quad*4+r, col(c)=lq
                facc[mt][r] += wv[r] * acc[r];
        }
        __builtin_amdgcn_s_setprio(0);
    }

    // ---- phase 4: transpose bounce in [c][px+pad] layout, all-b128 ----
    // facc[mt] holds px = mt*16+quad*4+{0..3} for cout n -> one ds_write_b128 each.
    // Stride 72 dwords: slot-group (2n+4mt+quad)%8 -> exactly 8 lanes/group =
    // wave64 b128 conflict-free minimum. Read side (2c+p4)%8 likewise.
    #pragma unroll
    for (int mt = 0; mt < 4; ++mt)
        *(f32x4*)&outt[n * 72 + mt * 16 + quad * 4] = facc[mt];
    __syncthreads();
    #pragma unroll
    for (int j = 0; j < 4; ++j) {
        const int idx = j * 256 + tid;          // 0..1023
        const int c   = idx >> 4;               // cout 0..63
        const int p4  = idx & 15;               // px/4 group 0..15
        const f32x4 v = *(const f32x4*)&outt[c * 72 + p4 * 4];    // ds_read_b128
        *(f32x4*)&out[((b * 64 + c) * 128 + row) * 128 + px0 + p4 * 4] = v;
    }
}

extern "C" void kernel_launch(void* const* d_in, const int* in_sizes, int n_in,
                              void* d_out, int out_size, void* d_ws, size_t ws_size,
                              hipStream_t stream) {
    const float* x  = (const float*)d_in[0];
    const float* gw = (const float*)d_in[1];
    const float* gb = (const float*)d_in[2];
    const float* ew = (const float*)d_in[3];
    const float* eb = (const float*)d_in[4];
    float* out        = (float*)d_out;
    float* logits_out = out + 8 * 64 * 128 * 128;
    unsigned short* wb = (unsigned short*)d_ws;      // 20480 chunks * 16 B = 327,680 B

    prep_w_kernel<<<dim3(80), dim3(256), 0, stream>>>(ew, eb, wb);
    moe_dense_kernel<<<dim3(2048), dim3(256), 0, stream>>>(
        x, gw, gb, wb, out, logits_out);
}

// Round 14
// 117.830 us; speedup vs baseline: 5.6321x; 2.8226x over previous
//
#include <hip/hip_runtime.h>
#include <cmath>

// B=8, Cin=16, H=W=128, Cout=64, E=16, K=2
typedef __attribute__((ext_vector_type(8))) short bf16x8;   // MFMA A/B frag
typedef __attribute__((ext_vector_type(4))) float f32x4;    // MFMA C/D frag

static __device__ __forceinline__ unsigned int f2bf(float f) {
    union { float f; unsigned int u; } v; v.f = f;
    unsigned int r = v.u + 0x7FFFu + ((v.u >> 16) & 1u);   // round-to-nearest-even
    return r >> 16;
}

// Pack 16 floats -> 16 bf16 -> two 16B LDS stores
static __device__ __forceinline__ void pack16(unsigned short* d, const float* v) {
    uint4 a, b2;
    a.x  = f2bf(v[0])  | (f2bf(v[1])  << 16);
    a.y  = f2bf(v[2])  | (f2bf(v[3])  << 16);
    a.z  = f2bf(v[4])  | (f2bf(v[5])  << 16);
    a.w  = f2bf(v[6])  | (f2bf(v[7])  << 16);
    b2.x = f2bf(v[8])  | (f2bf(v[9])  << 16);
    b2.y = f2bf(v[10]) | (f2bf(v[11]) << 16);
    b2.z = f2bf(v[12]) | (f2bf(v[13]) << 16);
    b2.w = f2bf(v[14]) | (f2bf(v[15]) << 16);
    *(uint4*)d       = a;
    *(uint4*)(d + 8) = b2;
}

// ---- prep: ew [16][64][144] fp32 + eb -> wb chunks [e][ks][nf][quad][lq] x 8 bf16 ----
// K-PERMUTED layout: k' = ky*48 + kx*16 + ci  (so im2col can write 16-channel runs
// with ds_write_b128). Chunk (e,ks,nf,quad,lq) holds k' = ks*32+quad*8 .. +7 for
// n = nf*16+lq. k'==144 holds bias (pairs with A's 1.0 column), k'>144 zero.
__global__ __launch_bounds__(256) void prep_w_kernel(const float* __restrict__ ew,
                                                     const float* __restrict__ eb,
                                                     unsigned short* __restrict__ wb) {
    const int c = blockIdx.x * 256 + threadIdx.x;
    if (c >= 20480) return;                     // 16 e * 1280 chunks
    const int e    = c / 1280;
    const int r    = c - e * 1280;
    const int ks   = r >> 8;                    // 0..4
    const int nf   = (r >> 6) & 3;
    const int quad = (r >> 4) & 3;
    const int lq   = r & 15;
    const int n    = nf * 16 + lq;
    const int k0   = ks * 32 + quad * 8;        // aligned-8 block of k'
    uint4 dv = make_uint4(0u, 0u, 0u, 0u);
    if (k0 < 144) {
        // k' block never crosses a (ky,kx) boundary (16-sized ci runs, 8-aligned k0)
        const int ky  = k0 / 48;
        const int kx  = (k0 >> 4) % 3;
        const int ci0 = k0 & 15;                // 0 or 8
        // source k = ci*9 + ky*3 + kx  (OIHW [E][64][16][3][3])
        const float* s = ew + (e * 64 + n) * 144 + ci0 * 9 + ky * 3 + kx;
        float v[8];
        #pragma unroll
        for (int j = 0; j < 8; ++j) v[j] = s[j * 9];
        dv.x = f2bf(v[0]) | (f2bf(v[1]) << 16);
        dv.y = f2bf(v[2]) | (f2bf(v[3]) << 16);
        dv.z = f2bf(v[4]) | (f2bf(v[5]) << 16);
        dv.w = f2bf(v[6]) | (f2bf(v[7]) << 16);
    } else if (k0 == 144) {
        dv.x = f2bf(eb[e * 64 + n]);            // bias column
    }
    *(uint4*)(wb + c * 8) = dv;
}

// ---- main: M=64 dense per-expert GEMM; LEAN 64-reg e-loop at 4 waves/SIMD ----
// grid: 2048 = b(8) x row(128) x half(2); block: 256 thr = 4 waves (wave = n-frag)
// REGISTER MODEL (rounds 5/8/9/11/12/13 measured): arch cap = 256/min_waves;
// unified usage = 2x arch cap (AGPR mirror) -> occupancy = min_waves exactly:
// (256,2)->128regs/2w(20%), (256,3)->84/3w(29%), (256,4)->64/4w(46%).
// Live set > cap => loop-resident scratch (~1 GB/dispatch). Round 13 proved even
// the af-pinned "baseline" (live ~150 @ cap 128) spills. Only spill-free config:
// round 10 (A-from-LDS, 84 regs, 203 us, latency-bound).
// THIS KERNEL: (256,4) cap 64, live ~56: facc 16 + bc 20 (single B buffer) +
// 1-2 A frags in flight + ptrs. A read per (mt,ks) from LDS (conflict-free b128:
// chunk-group (21*lq+quad+4*ks)%8 covers all 8). 16 waves/CU hide B's L2 latency.
// LDS: aliased 25.6KB (outt over Ab post-loop, barrier-guarded; verified r11/r12).
__global__ __launch_bounds__(256, 4) void moe_dense_kernel(
    const float* __restrict__ x,              // [8][16][128][128]
    const float* __restrict__ gw,             // [16][16]
    const float* __restrict__ gb,             // [16]
    const unsigned short* __restrict__ wb,    // [20480 chunks] bf16 (see prep)
    float* __restrict__ out,                  // [8][64][128][128]
    float* __restrict__ logits_out)           // [8][16][128][128]
{
    // 25,600 B union: [ Ab 21,504 B | wexp 4,096 B ]; outt (18,432 B) aliases Ab
    // after the post-e-loop barrier. wexp at 21,504 is outside outt -> never aliased.
    __shared__ __align__(16) unsigned char smem0[64 * 168 * 2 + 16 * 64 * 4];
    unsigned short* Ab   = (unsigned short*)smem0;            // [64][168] bf16
    float*          wexp = (float*)(smem0 + 64 * 168 * 2);    // [e][px] gate weight
    float*          outt = (float*)smem0;                     // [64][72] f32 (post-loop)

    const int tid = threadIdx.x;
    // T1 XCD swizzle (bijective: 2048 % 8 == 0): XCD i owns a contiguous bid range
    // -> adjacent rows/halves share halo rows + x panels in the same L2.
    const int bid = (blockIdx.x & 7) * 256 + (blockIdx.x >> 3);
    const int b   = bid >> 8;
    const int row = (bid >> 1) & 127;
    const int px0 = (bid & 1) << 6;

    const int lane = tid & 63;
    const int wave = tid >> 6;           // 0..3 = n-frag
    const int quad = lane >> 4;
    const int lq   = lane & 15;
    const int n    = lq + 16 * wave;     // this lane's cout

    const int px  = lane;
    const int col = px0 + px;

    // ---- phase 1 (single barrier at end): wave-specialized ----
    if (wave < 3) {
        // im2col for ky = wave; A row layout: k' = ky*48 + kx*16 + ci
        const int ky = wave;
        const int gr = row - 1 + ky;
        unsigned short* dst = Ab + px * 168 + ky * 48;
        if (gr < 0 || gr > 127) {        // wave-uniform branch (row 0 / row 127)
            const uint4 z = make_uint4(0u, 0u, 0u, 0u);
            *(uint4*)(dst)      = z; *(uint4*)(dst + 8)  = z;
            *(uint4*)(dst + 16) = z; *(uint4*)(dst + 24) = z;
            *(uint4*)(dst + 32) = z; *(uint4*)(dst + 40) = z;
        } else {
            float L[16], Mv[16], R[16];
            const float* xr = x + ((b * 16) * 128 + gr) * 128 + col;
            #pragma unroll
            for (int ci = 0; ci < 16; ++ci) {
                const float* p = xr + ci * 16384;
                Mv[ci] = p[0];
                L[ci]  = (col > 0)   ? p[-1] : 0.f;
                R[ci]  = (col < 127) ? p[1]  : 0.f;
            }
            pack16(dst,      L);         // kx = 0
            pack16(dst + 16, Mv);        // kx = 1
            pack16(dst + 32, R);         // kx = 2
        }
    } else {
        // gate logits + top-2 routing + logits_out + A k-pad, all in one wave
        // zero wexp first (this wave owns it pre-barrier; no ordering hazard)
        const float4 z4 = make_float4(0.f, 0.f, 0.f, 0.f);
        #pragma unroll
        for (int j = 0; j < 4; ++j)
            *(float4*)&wexp[(j * 64 + lane) * 4] = z4;
        float xv[16];
        const float* xp = x + (b * 16) * 16384 + row * 128 + col;
        #pragma unroll
        for (int ci = 0; ci < 16; ++ci) xv[ci] = xp[ci * 16384];
        float l[16];
        const int rbase = ((b * 16) * 128 + row) * 128 + col;
        #pragma unroll
        for (int o = 0; o < 16; ++o) {
            float acc = gb[o];
            #pragma unroll
            for (int i = 0; i < 16; ++i) acc += gw[o * 16 + i] * xv[i];
            l[o] = acc;
            logits_out[rbase + o * 16384] = acc;
        }
        float m = l[0];
        #pragma unroll
        for (int o = 1; o < 16; ++o) m = fmaxf(m, l[o]);
        float p0 = expf(l[0] - m), p1 = -1.f;
        int i0 = 0, i1 = 0;
        #pragma unroll
        for (int o = 1; o < 16; ++o) {
            float pv = expf(l[o] - m);
            if (pv > p0)      { p1 = p0; i1 = i0; p0 = pv; i0 = o; }
            else if (pv > p1) { p1 = pv; i1 = o; }
        }
        const float ws = p0 + p1;
        wexp[i0 * 64 + px] = p0 / ws;
        wexp[i1 * 64 + px] = p1 / ws;
        // A k-pad: k'144 = 1.0 (bias column), 145..167 = 0
        const uint4 z   = make_uint4(0u, 0u, 0u, 0u);
        const uint4 one = make_uint4(0x00003F80u, 0u, 0u, 0u);
        *(uint4*)(Ab + px * 168 + 144) = one;
        *(uint4*)(Ab + px * 168 + 152) = z;
        *(uint4*)(Ab + px * 168 + 160) = z;
    }
    __syncthreads();                     // Ab + wexp ready (persist through e-loop)

    // ---- phase 3: dense e-loop; LEAN register schedule (cap 64) ----
    // Per expert: load B (5 chunks, 20 regs) once; A streamed from LDS per (mt,ks).
    const unsigned short* arow = Ab + lq * 168 + quad * 8;   // + mt*2688 per tile
    const unsigned short* bpe  = wb + wave * 512 + lane * 8; // advances 10240/expert
    f32x4 facc[4];
    #pragma unroll
    for (int mt = 0; mt < 4; ++mt) facc[mt] = (f32x4){0.f, 0.f, 0.f, 0.f};

    #pragma unroll 1
    for (int e = 0; e < 16; ++e) {
        bf16x8 bc[5];
        #pragma unroll
        for (int ks = 0; ks < 5; ++ks) bc[ks] = *(const bf16x8*)(bpe + ks * 2048);
        bpe += 10240;
        __builtin_amdgcn_s_setprio(1);
        #pragma unroll
        for (int mt = 0; mt < 4; ++mt) {
            const unsigned short* ar = arow + mt * 2688;
            const f32x4 wv = *(const f32x4*)&wexp[e * 64 + mt * 16 + quad * 4];
            f32x4 acc = {0.f, 0.f, 0.f, 0.f};
            #pragma unroll
            for (int ks = 0; ks < 5; ++ks) {
                const bf16x8 a = *(const bf16x8*)(ar + ks * 32);   // ds_read_b128
                acc = __builtin_amdgcn_mfma_f32_16x16x32_bf16(a, bc[ks], acc, 0, 0, 0);
            }
            #pragma unroll
            for (int r = 0; r < 4; ++r)             // C/D: row(px)=quad*4+r, col(c)=lq
                facc[mt][r] += wv[r] * acc[r];
        }
        __builtin_amdgcn_s_setprio(0);
    }

    __syncthreads();                     // ALL waves done reading Ab/wexp -> outt may alias

    // ---- phase 4: transpose bounce in [c][px+pad] layout, all-b128 ----
    // facc[mt] holds px = mt*16+quad*4+{0..3} for cout n -> one ds_write_b128 each.
    // Stride 72 dwords: slot-group (2n+4mt+quad)%8 -> exactly 8 lanes/group =
    // wave64 b128 conflict-free minimum. Read side (2c+p4)%8 likewise.
    #pragma unroll
    for (int mt = 0; mt < 4; ++mt)
        *(f32x4*)&outt[n * 72 + mt * 16 + quad * 4] = facc[mt];
    __syncthreads();
    #pragma unroll
    for (int j = 0; j < 4; ++j) {
        const int idx = j * 256 + tid;          // 0..1023
        const int c   = idx >> 4;               // cout 0..63
        const int p4  = idx & 15;               // px/4 group 0..15
        const f32x4 v = *(const f32x4*)&outt[c * 72 + p4 * 4];    // ds_read_b128
        *(f32x4*)&out[((b * 64 + c) * 128 + row) * 128 + px0 + p4 * 4] = v;
    }
}

extern "C" void kernel_launch(void* const* d_in, const int* in_sizes, int n_in,
                              void* d_out, int out_size, void* d_ws, size_t ws_size,
                              hipStream_t stream) {
    const float* x  = (const float*)d_in[0];
    const float* gw = (const float*)d_in[1];
    const float* gb = (const float*)d_in[2];
    const float* ew = (const float*)d_in[3];
    const float* eb = (const float*)d_in[4];
    float* out        = (float*)d_out;
    float* logits_out = out + 8 * 64 * 128 * 128;
    unsigned short* wb = (unsigned short*)d_ws;      // 20480 chunks * 16 B = 327,680 B

    prep_w_kernel<<<dim3(80), dim3(256), 0, stream>>>(ew, eb, wb);
    moe_dense_kernel<<<dim3(2048), dim3(256), 0, stream>>>(
        x, gw, gb, wb, out, logits_out);
}